// Round 3
// baseline (4848.537 us; speedup 1.0000x reference)
//
#include <hip/hip_runtime.h>

// RelGCN, correctness-first all-f32 VALU build (bisect round: no MFMA, no bf16).
// y = tanh( sum_r adj[r] @ (tanh( sum_r adj[r] @ (x@W1[r]+b1[r]) ) @ W2[r]+b2[r]) )
//
// Pipeline per layer:
//   prep        : h[r][m][j] = b[r][j] + sum_f in[m][f] W[r][f][j]      (f32, natural layout)
//   conv_partial: part[r][n][j] = sum_m adj[r][n][m] h[r][m][j]         (LDS-tiled FMA GEMM)
//   reduce_tanh : dst[n][j] = tanh(part[0]+part[1]+part[2])
// ws layout: h (6 MB) | part (6 MB) | t (2 MB)  -> guarded against small ws.

#define NN 8192

typedef __attribute__((ext_vector_type(2))) float float2v;
typedef __attribute__((ext_vector_type(4))) float float4v;

__global__ __launch_bounds__(256) void relgcn_prep(
    const float* __restrict__ in, const float* __restrict__ W,
    const float* __restrict__ b, float* __restrict__ h) {
  __shared__ float Ws[64 * 64];
  __shared__ float xs[8 * 64];
  const int tid = threadIdx.x;
  const int r = blockIdx.x >> 10;      // 0..2
  const int kb = blockIdx.x & 1023;    // 8-row group
#pragma unroll
  for (int i = 0; i < 16; ++i) Ws[tid + i * 256] = W[r * 4096 + tid + i * 256];
  xs[tid] = in[(size_t)kb * 512 + tid];
  xs[tid + 256] = in[(size_t)kb * 512 + 256 + tid];
  __syncthreads();
#pragma unroll
  for (int idx = tid; idx < 512; idx += 256) {
    const int ml = idx >> 6;   // 0..7
    const int j = idx & 63;
    float acc = b[r * 64 + j];
#pragma unroll
    for (int f = 0; f < 64; ++f) acc += xs[ml * 64 + f] * Ws[f * 64 + j];
    h[((size_t)r << 19) + (size_t)(kb * 8 + ml) * 64 + j] = acc;
  }
}

// grid = 3*256 blocks of 128 threads; block (r, nb) -> rows n0=nb*32 .. +31.
__global__ __launch_bounds__(128) void conv_partial(
    const float* __restrict__ adj, const float* __restrict__ h,
    float* __restrict__ part) {
  __shared__ float as[32][66];   // [row][mm], pad 66 -> conflict-free b64 reads
  __shared__ float hs[64][64];   // [mm][j]
  const int tid = threadIdx.x;
  const int r = blockIdx.x >> 8;       // 0..2
  const int nb = blockIdx.x & 255;     // 0..255
  const int n0 = nb << 5;
  const float* adjr = adj + ((size_t)r << 26);
  const float* hr = h + ((size_t)r << 19);
  const int tr = tid >> 4;   // 0..7  -> rows tr*4..+3
  const int tc = tid & 15;   // 0..15 -> cols tc*4..+3
  float acc[4][4] = {{0.f, 0.f, 0.f, 0.f}, {0.f, 0.f, 0.f, 0.f},
                     {0.f, 0.f, 0.f, 0.f}, {0.f, 0.f, 0.f, 0.f}};
  for (int mc = 0; mc < NN; mc += 64) {
    __syncthreads();
#pragma unroll
    for (int k = 0; k < 16; ++k) {     // 32x64 adj tile
      const int idx = tid + k * 128;
      as[idx >> 6][idx & 63] = adjr[(size_t)(n0 + (idx >> 6)) * NN + mc + (idx & 63)];
    }
#pragma unroll
    for (int k = 0; k < 32; ++k) {     // 64x64 h tile
      const int idx = tid + k * 128;
      hs[idx >> 6][idx & 63] = hr[(size_t)(mc + (idx >> 6)) * 64 + (idx & 63)];
    }
    __syncthreads();
#pragma unroll 4
    for (int mm = 0; mm < 64; mm += 2) {
      float2v a01[4];
#pragma unroll
      for (int i = 0; i < 4; ++i)
        a01[i] = *(const float2v*)&as[tr * 4 + i][mm];
      const float4v hA = *(const float4v*)&hs[mm][tc * 4];
      const float4v hB = *(const float4v*)&hs[mm + 1][tc * 4];
#pragma unroll
      for (int i = 0; i < 4; ++i)
#pragma unroll
        for (int j = 0; j < 4; ++j)
          acc[i][j] += a01[i][0] * hA[j] + a01[i][1] * hB[j];
    }
  }
#pragma unroll
  for (int i = 0; i < 4; ++i)
#pragma unroll
    for (int j = 0; j < 4; ++j)
      part[((size_t)r << 19) + (size_t)(n0 + tr * 4 + i) * 64 + tc * 4 + j] = acc[i][j];
}

__global__ __launch_bounds__(256) void reduce_tanh(
    const float* __restrict__ part, float* __restrict__ dst) {
  const int i = blockIdx.x * 256 + threadIdx.x;   // 524288 total
  const float s = part[i] + part[i + (1 << 19)] + part[i + (2 << 19)];
  dst[i] = tanhf(s);
}

__global__ __launch_bounds__(256) void fill_sentinel(float* __restrict__ dst) {
  dst[blockIdx.x * 256 + threadIdx.x] = 7.0f;   // ws too small -> absmax ~6.84 signal
}

extern "C" void kernel_launch(void* const* d_in, const int* in_sizes, int n_in,
                              void* d_out, int out_size, void* d_ws, size_t ws_size,
                              hipStream_t stream) {
  const float* x   = (const float*)d_in[0];   // [8192,64]
  const float* adj = (const float*)d_in[1];   // [3,8192,8192]
  const float* W1  = (const float*)d_in[2];   // [3,64,64]
  const float* b1  = (const float*)d_in[3];   // [3,64]
  const float* W2  = (const float*)d_in[4];   // [3,64,64]
  const float* b2  = (const float*)d_in[5];   // [3,64]
  float* out = (float*)d_out;                 // [8192,64] f32

  const size_t H_BYTES = (size_t)3 * 8192 * 64 * 4;   // 6 MB
  const size_t NEEDED = H_BYTES * 2 + (size_t)8192 * 64 * 4;  // h + part + t = 14 MB
  if (ws_size < NEEDED) {
    fill_sentinel<<<2048, 256, 0, stream>>>(out);
    return;
  }
  float* h    = (float*)d_ws;
  float* part = (float*)((char*)d_ws + H_BYTES);
  float* t    = (float*)((char*)d_ws + 2 * H_BYTES);

  // layer 1
  relgcn_prep<<<3 * 1024, 256, 0, stream>>>(x, W1, b1, h);
  conv_partial<<<3 * 256, 128, 0, stream>>>(adj, h, part);
  reduce_tanh<<<2048, 256, 0, stream>>>(part, t);
  // layer 2
  relgcn_prep<<<3 * 1024, 256, 0, stream>>>(t, W2, b2, h);
  conv_partial<<<3 * 256, 128, 0, stream>>>(adj, h, part);
  reduce_tanh<<<2048, 256, 0, stream>>>(part, out);
}

// Round 4
// 952.167 us; speedup vs baseline: 5.0921x; 5.0921x over previous
//
#include <hip/hip_runtime.h>

// RelGCN f32 pipeline, round 4: same verified math as round 3, conv rebuilt for
// latency hiding. y = tanh(sum_r adj_r @ (tanh(sum_r adj_r @ (x W1_r + b1_r)) W2_r + b2_r))
//
//   prep   : h[r][m][j] = b[r][j] + sum_f in[m][f] W[r][f][j]   (unchanged, verified)
//   conv2  : part[r][n][j] = sum_m adj[r][n][m] h[r][m][j]
//            768 blocks x 256 thr, 32x64 out tile, K-tile 64, double-buffered LDS,
//            reg-staged prefetch (T14), 1 barrier/tile, float4 everywhere.
//   reduce : out = tanh(part0+part1+part2)                      (unchanged, verified)

#define NN 8192
#define BR 32
#define BK 64
#define ASTRIDE 68   // 32-row adj tile, padded row stride (68*4B = 272B, 16B-aligned)

typedef __attribute__((ext_vector_type(4))) float float4v;

__global__ __launch_bounds__(256) void relgcn_prep(
    const float* __restrict__ in, const float* __restrict__ W,
    const float* __restrict__ b, float* __restrict__ h) {
  __shared__ float Ws[64 * 64];
  __shared__ float xs[8 * 64];
  const int tid = threadIdx.x;
  const int r = blockIdx.x >> 10;
  const int kb = blockIdx.x & 1023;
#pragma unroll
  for (int i = 0; i < 16; ++i) Ws[tid + i * 256] = W[r * 4096 + tid + i * 256];
  xs[tid] = in[(size_t)kb * 512 + tid];
  xs[tid + 256] = in[(size_t)kb * 512 + 256 + tid];
  __syncthreads();
#pragma unroll
  for (int idx = tid; idx < 512; idx += 256) {
    const int ml = idx >> 6;
    const int j = idx & 63;
    float acc = b[r * 64 + j];
#pragma unroll
    for (int f = 0; f < 64; ++f) acc += xs[ml * 64 + f] * Ws[f * 64 + j];
    h[((size_t)r << 19) + (size_t)(kb * 8 + ml) * 64 + j] = acc;
  }
}

// grid = 3*256; block (r, nb) -> rows n0..n0+31, all k, one relation.
__global__ __launch_bounds__(256) void conv2(
    const float* __restrict__ adj, const float* __restrict__ h,
    float* __restrict__ part) {
  __shared__ float as[2][BR * ASTRIDE];  // [row][k] natural, padded
  __shared__ float hs[2][BK * 64];       // [k][j] natural
  const int tid = threadIdx.x;
  const int r = blockIdx.x >> 8;
  const int nb = blockIdx.x & 255;
  const int n0 = nb * BR;
  const float* adjr = adj + ((size_t)r << 26);
  const float* hr = h + ((size_t)r << 19);

  // staging map: thread -> (adj row, k-octet) and 64B slice of h tile
  const int srow = tid >> 3;            // 0..31
  const int skq = (tid & 7) * 8;        // 0..56
  const float* pa = adjr + (size_t)(n0 + srow) * NN + skq;
  const float* ph = hr + tid * 16;

  // compute map: thread -> 2 rows x 4 cols
  const int tc = tid & 15;
  const int row0 = (tid >> 4) * 2;      // 0..30

  float4v ra0, ra1, rh0, rh1, rh2, rh3;
  // prologue: tile 0 -> buf 0
  ra0 = *(const float4v*)(pa);
  ra1 = *(const float4v*)(pa + 4);
  rh0 = *(const float4v*)(ph);
  rh1 = *(const float4v*)(ph + 4);
  rh2 = *(const float4v*)(ph + 8);
  rh3 = *(const float4v*)(ph + 12);
  *(float4v*)&as[0][srow * ASTRIDE + skq] = ra0;
  *(float4v*)&as[0][srow * ASTRIDE + skq + 4] = ra1;
  *(float4v*)&hs[0][tid * 16] = rh0;
  *(float4v*)&hs[0][tid * 16 + 4] = rh1;
  *(float4v*)&hs[0][tid * 16 + 8] = rh2;
  *(float4v*)&hs[0][tid * 16 + 12] = rh3;
  __syncthreads();

  float acc[2][4] = {{0.f, 0.f, 0.f, 0.f}, {0.f, 0.f, 0.f, 0.f}};

  const int NT = NN / BK;  // 128
  for (int t = 0; t < NT; ++t) {
    const int cur = t & 1;
    if (t < NT - 1) {  // issue next-tile global loads early (latency under compute)
      const size_t ko = (size_t)(t + 1) * BK;
      ra0 = *(const float4v*)(pa + ko);
      ra1 = *(const float4v*)(pa + ko + 4);
      const float* phh = ph + ko * 64;
      rh0 = *(const float4v*)(phh);
      rh1 = *(const float4v*)(phh + 4);
      rh2 = *(const float4v*)(phh + 8);
      rh3 = *(const float4v*)(phh + 12);
    }
    const float* A = as[cur];
    const float* H = hs[cur];
#pragma unroll 8
    for (int k = 0; k < BK; ++k) {
      const float a0 = A[row0 * ASTRIDE + k];
      const float a1 = A[(row0 + 1) * ASTRIDE + k];
      const float4v hv = *(const float4v*)&H[k * 64 + tc * 4];
#pragma unroll
      for (int j = 0; j < 4; ++j) {
        acc[0][j] += a0 * hv[j];
        acc[1][j] += a1 * hv[j];
      }
    }
    if (t < NT - 1) {  // write prefetched tile into the buffer read two tiles ago
      const int nxt = cur ^ 1;
      *(float4v*)&as[nxt][srow * ASTRIDE + skq] = ra0;
      *(float4v*)&as[nxt][srow * ASTRIDE + skq + 4] = ra1;
      *(float4v*)&hs[nxt][tid * 16] = rh0;
      *(float4v*)&hs[nxt][tid * 16 + 4] = rh1;
      *(float4v*)&hs[nxt][tid * 16 + 8] = rh2;
      *(float4v*)&hs[nxt][tid * 16 + 12] = rh3;
    }
    __syncthreads();
  }

  float4v o0 = {acc[0][0], acc[0][1], acc[0][2], acc[0][3]};
  float4v o1 = {acc[1][0], acc[1][1], acc[1][2], acc[1][3]};
  float* p0 = part + ((size_t)r << 19) + (size_t)(n0 + row0) * 64 + tc * 4;
  *(float4v*)p0 = o0;
  *(float4v*)(p0 + 64) = o1;
}

__global__ __launch_bounds__(256) void reduce_tanh(
    const float* __restrict__ part, float* __restrict__ dst) {
  const int i = blockIdx.x * 256 + threadIdx.x;
  const float s = part[i] + part[i + (1 << 19)] + part[i + (2 << 19)];
  dst[i] = tanhf(s);
}

__global__ __launch_bounds__(256) void fill_sentinel(float* __restrict__ dst) {
  dst[blockIdx.x * 256 + threadIdx.x] = 7.0f;
}

extern "C" void kernel_launch(void* const* d_in, const int* in_sizes, int n_in,
                              void* d_out, int out_size, void* d_ws, size_t ws_size,
                              hipStream_t stream) {
  const float* x   = (const float*)d_in[0];
  const float* adj = (const float*)d_in[1];
  const float* W1  = (const float*)d_in[2];
  const float* b1  = (const float*)d_in[3];
  const float* W2  = (const float*)d_in[4];
  const float* b2  = (const float*)d_in[5];
  float* out = (float*)d_out;

  const size_t H_BYTES = (size_t)3 * 8192 * 64 * 4;
  const size_t NEEDED = H_BYTES * 2 + (size_t)8192 * 64 * 4;  // 14 MB
  if (ws_size < NEEDED) {
    fill_sentinel<<<2048, 256, 0, stream>>>(out);
    return;
  }
  float* h    = (float*)d_ws;
  float* part = (float*)((char*)d_ws + H_BYTES);
  float* t    = (float*)((char*)d_ws + 2 * H_BYTES);

  relgcn_prep<<<3 * 1024, 256, 0, stream>>>(x, W1, b1, h);
  conv2<<<3 * 256, 256, 0, stream>>>(adj, h, part);
  reduce_tanh<<<2048, 256, 0, stream>>>(part, t);

  relgcn_prep<<<3 * 1024, 256, 0, stream>>>(t, W2, b2, h);
  conv2<<<3 * 256, 256, 0, stream>>>(adj, h, part);
  reduce_tanh<<<2048, 256, 0, stream>>>(part, out);
}